// Round 8
// baseline (394.201 us; speedup 1.0000x reference)
//
#include <hip/hip_runtime.h>
#include <math.h>

#define V 2
#define NN 100000
#define KK 8
#define DD 128
#define TILE_N 128
#define SL 132
#define NT 782            /* ceil(100000/128) */
#define CH 8              /* tiles per maha block */
#define CPX 13            /* chunks per XCD: 8*13=104 >= ceil(782/8)=98 */
#define NPAD 100096       /* NT*128 */
#define LOG2PI 1.8378770664093454f
#define LOG_1EM6 -13.815510557964274f

// Packed triangular W image (per r): 4 row-blocks of 32 rows; block b stores
// cols 0..32(b+1)-1, row stride 64(b+1) bytes. Within each block, the 16-byte
// chunk (ri, g) lives at byte ((ri*64*(b+1) + g*16) XOR ((ri&7)<<4)) — proven:
// bank conflicts 30.4M -> 4.8M. hi block byte bases {0,2048,6144,12288};
// lo copy at +20480 B. Total 40960 B.
#define IMG_PB 40960
#define IMG_LO_US 10240     /* ushort offset of lo half */

// ws layout (bytes):
//  IMG:  [16][40960]  packed+swizzled bf16 triangular image (hi then lo)
//  LF:   [16][69632]  L fp32 row-major stride 132 (67584 B used)
//  B:    [16][128] float
//  C:    [16] float
//  MAHA: [16][NPAD] float
#define LF_B   1114112
#define LF_STRIDE 69632
#define BV_B   2228224
#define C_B    2236416
#define MAHA_B 2236480

// out layout (floats): energies [N][V] | weights [N][V] | total_energies | total_penalty
#define OUT_W_OFF (NN*V)
#define OUT_TE (2*NN*V)
#define OUT_TP (2*NN*V + 1)

typedef __attribute__((ext_vector_type(8))) short bf16x8;
typedef __attribute__((ext_vector_type(4))) float f32x4;
typedef __attribute__((ext_vector_type(4))) unsigned u32x4;

__device__ __forceinline__ unsigned short f2bf_rtn(float f) {
    unsigned u = __builtin_bit_cast(unsigned, f);
    unsigned r = u + 0x7FFFu + ((u >> 16) & 1u);
    return (unsigned short)(r >> 16);
}
__device__ __forceinline__ float bf2f(unsigned short h) {
    unsigned u = ((unsigned)h) << 16;
    return __builtin_bit_cast(float, u);
}

// Cheap split: hi = truncation (packed 2-at-a-time via v_perm), lo = exact
// residual rounded half-up (proven rounds 0/2/3/5/6/7: absmax identical).
__device__ __forceinline__ void cvt_pair(float f0, float f1, unsigned& hi, unsigned& lo) {
    unsigned u0 = __builtin_bit_cast(unsigned, f0);
    unsigned u1 = __builtin_bit_cast(unsigned, f1);
    hi = __builtin_amdgcn_perm(u1, u0, 0x07060302u);   // [bf(f1) : bf(f0)]
    float r0 = f0 - __builtin_bit_cast(float, u0 & 0xFFFF0000u);
    float r1 = f1 - __builtin_bit_cast(float, u1 & 0xFFFF0000u);
    unsigned v0 = __builtin_bit_cast(unsigned, r0) + 0x8000u;
    unsigned v1 = __builtin_bit_cast(unsigned, r1) + 0x8000u;
    lo = __builtin_amdgcn_perm(v1, v0, 0x07060302u);
}

__global__ void zero_kernel(float* out) {
    int t = threadIdx.x;
    if (t < 2) out[OUT_TE + t] = 0.0f;
}

// One block of 256 threads per (v,k): panel Cholesky,
// forward solve L b = mu, write L + b + c + penalty/logdet.
__global__ __launch_bounds__(256) void prep_chol(const float* __restrict__ phi,
                                                 const float* __restrict__ mu,
                                                 const float* __restrict__ sigma,
                                                 void* __restrict__ wsv,
                                                 float* __restrict__ out) {
    __shared__ float Lf[DD * SL];          // L row-major, stride 132 (upper zeroed)
    __shared__ float P[8][SL];             // current panel, col-major
    __shared__ float dvec[DD];             // raw pivots d_c = L_cc^2
    __shared__ float mulds[DD];
    __shared__ float red[256];
    __shared__ float Bv[8];
    __shared__ float Bb[DD];

    const int tid = threadIdx.x;
    const int vk  = blockIdx.x;
    const int v   = vk >> 3;
    const int k   = vk & 7;
    const int R   = tid >> 4;
    const int C   = tid & 15;

    if (tid < DD) mulds[tid] = mu[vk * DD + tid];

    float A[8][8];
    const float* sig = sigma + (size_t)vk * DD * DD;
    float pen = 0.0f;
    #pragma unroll
    for (int a = 0; a < 8; ++a) {
        const float4* p4 = (const float4*)(sig + (size_t)(8 * R + a) * DD + 8 * C);
        float4 x = p4[0], y = p4[1];
        A[a][0] = x.x; A[a][1] = x.y; A[a][2] = x.z; A[a][3] = x.w;
        A[a][4] = y.x; A[a][5] = y.y; A[a][6] = y.z; A[a][7] = y.w;
        if (R == C) A[a][a] += 1e-6f;
    }
    if (R == C) {
        #pragma unroll
        for (int a = 0; a < 8; ++a) pen += 1.0f / (A[a][a] + 1e-12f);
    }

    for (int i = tid; i < DD * SL; i += 256) Lf[i] = 0.0f;

    red[tid] = pen;
    __syncthreads();
    for (int s = 128; s > 0; s >>= 1) {
        if (tid < s) red[tid] += red[tid + s];
        __syncthreads();
    }
    if (tid == 0) atomicAdd(&out[OUT_TP], red[0]);
    __syncthreads();

    // ---- 16 panel phases ----
    for (int p = 0; p < 16; ++p) {
        if (C == p && R >= p) {
            #pragma unroll
            for (int b = 0; b < 8; ++b) {
                *(float4*)&P[b][8 * R]     = make_float4(A[0][b], A[1][b], A[2][b], A[3][b]);
                *(float4*)&P[b][8 * R + 4] = make_float4(A[4][b], A[5][b], A[6][b], A[7][b]);
            }
        }
        __syncthreads();

        if (tid < 64) {
            const int lane = tid;
            const int r1 = 8 * p + lane;
            const int r2 = r1 + 64;
            const bool ok2 = (r2 < DD);
            float pr1[8], pr2[8], rs[8];
            #pragma unroll
            for (int j = 0; j < 8; ++j) {
                pr1[j] = (r1 < DD) ? P[j][r1] : 0.0f;
                pr2[j] = ok2 ? P[j][r2] : 0.0f;
            }
            #pragma unroll
            for (int j = 0; j < 8; ++j) {
                if (lane >= j && lane < 8) Bv[lane] = pr1[j];
                __builtin_amdgcn_wave_barrier();
                float bv[8];
                #pragma unroll
                for (int m = 0; m < 8; ++m) bv[m] = Bv[m];
                __builtin_amdgcn_wave_barrier();
                float piv = bv[j];
                if (lane == j) dvec[8 * p + j] = piv;
                float inv2 = 1.0f / piv;
                rs[j] = rsqrtf(piv);
                float m1 = pr1[j] * inv2;
                float m2 = pr2[j] * inv2;
                #pragma unroll
                for (int j2 = 0; j2 < 8; ++j2) {
                    if (j2 > j) {
                        if (lane > j) pr1[j2] -= m1 * bv[j2];
                        pr2[j2] -= m2 * bv[j2];
                    }
                }
            }
            #pragma unroll
            for (int j = 0; j < 8; ++j) {
                if (r1 < DD) {
                    float v1 = (lane >= j) ? pr1[j] * rs[j] : 0.0f;
                    P[j][r1] = v1;
                    Lf[r1 * SL + 8 * p + j] = v1;
                }
                if (ok2) {
                    float v2 = pr2[j] * rs[j];
                    P[j][r2] = v2;
                    Lf[r2 * SL + 8 * p + j] = v2;
                }
            }
        }
        __syncthreads();

        if (C > p && R >= p) {
            #pragma unroll
            for (int j = 0; j < 8; ++j) {
                float4 a0 = *(const float4*)&P[j][8 * R];
                float4 a1 = *(const float4*)&P[j][8 * R + 4];
                float4 b0 = *(const float4*)&P[j][8 * C];
                float4 b1 = *(const float4*)&P[j][8 * C + 4];
                float ra[8] = {a0.x, a0.y, a0.z, a0.w, a1.x, a1.y, a1.z, a1.w};
                float rb[8] = {b0.x, b0.y, b0.z, b0.w, b1.x, b1.y, b1.z, b1.w};
                #pragma unroll
                for (int a = 0; a < 8; ++a)
                    #pragma unroll
                    for (int b = 0; b < 8; ++b)
                        A[a][b] -= ra[a] * rb[b];
            }
        }
        __syncthreads();
    }

    // forward solve L b = mu (wave 0, wave-synchronous)
    if (tid < 64) {
        const int lane = tid;
        float acc0 = mulds[lane];
        float acc1 = mulds[lane + 64];
        for (int j = 0; j < DD; ++j) {
            if (j < 64) { if (lane == j)      Bb[j] = acc0 / Lf[j * SL + j]; }
            else        { if (lane == j - 64) Bb[j] = acc1 / Lf[j * SL + j]; }
            __builtin_amdgcn_wave_barrier();
            float bj = Bb[j];
            __builtin_amdgcn_wave_barrier();
            if (lane > j)      acc0 -= Lf[lane * SL + j] * bj;
            if (lane + 64 > j) acc1 -= Lf[(lane + 64) * SL + j] * bj;
        }
    }
    __syncthreads();
    if (tid < DD) ((float*)((char*)wsv + BV_B))[vk * DD + tid] = Bb[tid];

    // write L to global (fp32, stride 132)
    {
        float4* Lg = (float4*)((char*)wsv + LF_B + (size_t)vk * LF_STRIDE);
        const float4* Ls4 = (const float4*)Lf;
        for (int i = tid; i < DD * SL / 4; i += 256) Lg[i] = Ls4[i];
    }

    // logdet = sum log d_c (clipped) + c_k
    red[tid] = (tid < DD) ? logf(dvec[tid]) : 0.0f;
    __syncthreads();
    for (int s = 128; s > 0; s >>= 1) {
        if (tid < s) red[tid] += red[tid + s];
        __syncthreads();
    }
    if (tid == 0) {
        float logdet_c = fmaxf(red[0], LOG_1EM6);
        const float* ph = phi + v * KK;
        float m = ph[0];
        for (int i = 1; i < KK; ++i) m = fmaxf(m, ph[i]);
        float s = 0.0f;
        for (int i = 0; i < KK; ++i) s += expf(ph[i] - m);
        float logpi = ph[k] - m - logf(s);
        ((float*)((char*)wsv + C_B))[vk] = logpi - 0.5f * logdet_c - 0.5f * (float)DD * LOG2PI;
    }
}

// 64 blocks: (vk, column-group). Each block computes 32 columns of W = L^{-1}
// (8 lanes per column) and packs them into the packed+SWIZZLED triangular image.
__global__ __launch_bounds__(256) void prep_trsm(void* __restrict__ wsv) {
    __shared__ float Ls[DD * SL];
    __shared__ float Wc[32][SL];

    const int tid = threadIdx.x;
    const int vk  = blockIdx.x >> 2;
    const int cg  = blockIdx.x & 3;

    const float4* Lg = (const float4*)((const char*)wsv + LF_B + (size_t)vk * LF_STRIDE);
    float4* Ls4 = (float4*)Ls;
    for (int i = tid; i < DD * SL / 4; i += 256) Ls4[i] = Lg[i];
    __syncthreads();

    const int c   = tid >> 3;          // local column 0..31
    const int par = tid & 7;
    const int j   = 4 * c + cg;        // global column

    for (int e = par; e < SL; e += 8) Wc[c][e] = 0.0f;
    if (par == 0) Wc[c][j] = 1.0f / Ls[j * SL + j];
    __builtin_amdgcn_wave_barrier();

    const int pbase = j & ~3;
    for (int i = j + 1; i < DD; ++i) {
        float s = 0.0f;
        for (int p4 = pbase + 4 * par; p4 < i; p4 += 32) {
            float4 lf = *(const float4*)&Ls[i * SL + p4];
            float4 wc = *(const float4*)&Wc[c][p4];
            s += lf.x * wc.x + lf.y * wc.y + lf.z * wc.z + lf.w * wc.w;
        }
        s += __shfl_xor(s, 1, 64);
        s += __shfl_xor(s, 2, 64);
        s += __shfl_xor(s, 4, 64);
        if (par == 0) Wc[c][i] = -s / Ls[i * SL + i];
        __builtin_amdgcn_wave_barrier();
    }

    // pack column j into the packed+swizzled triangular image:
    // row i in row-block b=i>>5 (col stored only if (j>>5) <= b); chunk byte
    // offset within block = (ri*64*(b+1) + (j>>3)*16) ^ ((ri&7)<<4).
    unsigned short* Gh = (unsigned short*)((char*)wsv + (size_t)vk * IMG_PB);
    for (int i2 = par; i2 < DD; i2 += 8) {
        const int b = i2 >> 5;
        if ((j >> 5) > b) continue;            // col outside this block's range
        const int ri   = i2 & 31;
        const int hbb  = (b == 0 ? 0 : b == 1 ? 2048 : b == 2 ? 6144 : 12288);
        const int cb   = ri * 64 * (b + 1) + (j >> 3) * 16;
        const int sw   = cb ^ ((ri & 7) << 4);
        const int us   = ((hbb + sw) >> 1) + (j & 7);
        float f = (i2 >= j) ? Wc[c][i2] : 0.0f;
        unsigned short h = f2bf_rtn(f);
        unsigned short l = f2bf_rtn(f - bf2f(h));
        Gh[us] = h;
        Gh[us + IMG_LO_US] = l;
    }
}

// 1-D grid of 1664 blocks, XCD-aware decode (proven: FETCH 402->65MB).
// No launch-bound cap (cap/2 law, rounds 1/4/5/6). This round: recombine the
// two proven-but-separate levers — round-3's z-prefetch double-buffer and
// high MFMA ILP — on top of the small-acc structure. nt processed in PAIRS
// (nt0=2p, nt1=2p+1 share row-block b=p and ds-range) giving 4 independent
// MFMA chains (2 mt x 2 nt); prefetch hides next tile's z latency under the
// current tile's 120 MFMAs. Live set ~150 regs: no spill at default cap,
// LDS still allows 4 blocks/CU, VGPR ~3 blocks.
__global__ __launch_bounds__(256) void maha_kernel(const float* __restrict__ z,
                                                   void* __restrict__ wsv) {
    __shared__ unsigned short wl[IMG_PB / 2];

    const int tid  = threadIdx.x;
    const int lane = tid & 63;
    const int wave = tid >> 6;
    const int quad = lane >> 4;
    const int l16  = lane & 15;
    const int swz  = (l16 & 7) << 4;    // read-side XOR (rows map to l16)

    const int bi    = blockIdx.x;       // 0..1663
    const int xcd   = bi & 7;
    const int jj    = bi >> 3;          // 0..207
    const int r     = jj & 15;          // fast: 16 r's of a chunk adjacent on XCD
    const int lc    = jj >> 4;          // 0..12
    const int chunk = xcd * CPX + lc;   // 0..103
    const int vv    = r >> 3;

    if (chunk * CH >= NT) return;       // fully-empty chunk (98..103): skip staging

    // stage packed W_r (10 x 4KB chunks, exact: IMG_PB = 10*4096) — linear
    // copy; the swizzle already lives in the global image.
    {
        const char* src = (const char*)wsv + (size_t)r * IMG_PB;
        char* dst = (char*)wl;
        const int lane_off = wave * 1024 + lane * 16;
        #pragma unroll
        for (int t = 0; t < 10; ++t)
            __builtin_amdgcn_global_load_lds(
                (const __attribute__((address_space(1))) void*)(src + t * 4096 + lane_off),
                (__attribute__((address_space(3))) void*)(dst + t * 4096 + wave * 1024),
                16, 0, 0);
    }

    // b vector -> 8 registers (b[nt*16+l16]); tiny, L2-hot
    float blr[8];
    {
        const float* bvp = (const float*)((const char*)wsv + BV_B) + r * DD;
        #pragma unroll
        for (int nt = 0; nt < 8; ++nt) blr[nt] = bvp[nt * 16 + l16];
    }
    __syncthreads();   // single drain; nothing in-flight afterwards

    const float* zbase = z + (size_t)vv * NN * DD;
    float* mrow = (float*)((char*)wsv + MAHA_B) + (size_t)r * NPAD;
    const char* wlb = (const char*)wl;

    float4 pre[2][4][2];   // raw z prefetch buffer: [mt][ds][half], 32 VGPRs

    auto load_tile = [&](int tt) {
        #pragma unroll
        for (int mt = 0; mt < 2; ++mt) {
            const int n = tt * TILE_N + wave * 32 + mt * 16 + l16;
            const bool ok = (n < NN);
            const float* zp = zbase + (size_t)n * DD + quad * 8;
            #pragma unroll
            for (int ds = 0; ds < 4; ++ds) {
                if (ok) {
                    pre[mt][ds][0] = *(const float4*)(zp + ds * 32);
                    pre[mt][ds][1] = *(const float4*)(zp + ds * 32 + 4);
                } else {
                    pre[mt][ds][0] = make_float4(0.f, 0.f, 0.f, 0.f);
                    pre[mt][ds][1] = make_float4(0.f, 0.f, 0.f, 0.f);
                }
            }
        }
    };

    load_tile(chunk * CH);   // prologue prefetch

    for (int ti = 0; ti < CH; ++ti) {
        const int t = chunk * CH + ti;
        if (t >= NT) break;
        const int n0 = t * TILE_N;

        // convert whole tile upfront (consumes pre -> frees it for reissue)
        u32x4 zh[2][4], zl[2][4];
        #pragma unroll
        for (int mt = 0; mt < 2; ++mt)
            #pragma unroll
            for (int ds = 0; ds < 4; ++ds) {
                float4 a = pre[mt][ds][0];
                float4 b = pre[mt][ds][1];
                unsigned h0, l0, h1, l1, h2, l2, h3, l3;
                cvt_pair(a.x, a.y, h0, l0);
                cvt_pair(a.z, a.w, h1, l1);
                cvt_pair(b.x, b.y, h2, l2);
                cvt_pair(b.z, b.w, h3, l3);
                u32x4 th, tl;
                th[0] = h0; th[1] = h1; th[2] = h2; th[3] = h3;
                tl[0] = l0; tl[1] = l1; tl[2] = l2; tl[3] = l3;
                zh[mt][ds] = th;
                zl[mt][ds] = tl;
            }

        // issue next tile's loads; they fly under the MFMA below
        if (ti + 1 < CH && t + 1 < NT) load_tile(t + 1);

        // nt-pair loop: nt0=2p and nt1=2p+1 share row-block b=p and ds-range
        // -> 4 independent MFMA chains (a00,a01,a10,a11), squared into p[] at
        // pair end. Only 4 f32x4 accs live.
        float p[2][4] = {{0.f, 0.f, 0.f, 0.f}, {0.f, 0.f, 0.f, 0.f}};
        #pragma unroll
        for (int np = 0; np < 4; ++np) {
            const int nt0 = 2 * np;
            const int nt1 = nt0 + 1;
            const int ri0 = l16;
            const int ri1 = 16 + l16;
            const int hbb = (np == 0 ? 0 : np == 1 ? 2048 : np == 2 ? 6144 : 12288);
            const int rstride = 64 * (np + 1);
            f32x4 a00 = (f32x4)(-blr[nt0]);   // (mt0, nt0)
            f32x4 a10 = (f32x4)(-blr[nt0]);   // (mt1, nt0)
            f32x4 a01 = (f32x4)(-blr[nt1]);   // (mt0, nt1)
            f32x4 a11 = (f32x4)(-blr[nt1]);   // (mt1, nt1)
            #pragma unroll
            for (int ds = 0; ds <= np; ++ds) {   // W tile zero for ds > np
                const int g    = ds * 4 + quad;
                const int off0 = hbb + ((ri0 * rstride + g * 16) ^ swz);
                const int off1 = hbb + ((ri1 * rstride + g * 16) ^ swz);
                bf16x8 bh0  = *(const bf16x8*)(wlb + off0);
                bf16x8 blo0 = *(const bf16x8*)(wlb + off0 + 2 * IMG_LO_US);
                bf16x8 bh1  = *(const bf16x8*)(wlb + off1);
                bf16x8 blo1 = *(const bf16x8*)(wlb + off1 + 2 * IMG_LO_US);
                bf16x8 ah0 = __builtin_bit_cast(bf16x8, zh[0][ds]);
                bf16x8 al0 = __builtin_bit_cast(bf16x8, zl[0][ds]);
                bf16x8 ah1 = __builtin_bit_cast(bf16x8, zh[1][ds]);
                bf16x8 al1 = __builtin_bit_cast(bf16x8, zl[1][ds]);
                a00 = __builtin_amdgcn_mfma_f32_16x16x32_bf16(ah0, bh0,  a00, 0, 0, 0);
                a10 = __builtin_amdgcn_mfma_f32_16x16x32_bf16(ah1, bh0,  a10, 0, 0, 0);
                a01 = __builtin_amdgcn_mfma_f32_16x16x32_bf16(ah0, bh1,  a01, 0, 0, 0);
                a11 = __builtin_amdgcn_mfma_f32_16x16x32_bf16(ah1, bh1,  a11, 0, 0, 0);
                a00 = __builtin_amdgcn_mfma_f32_16x16x32_bf16(ah0, blo0, a00, 0, 0, 0);
                a10 = __builtin_amdgcn_mfma_f32_16x16x32_bf16(ah1, blo0, a10, 0, 0, 0);
                a01 = __builtin_amdgcn_mfma_f32_16x16x32_bf16(ah0, blo1, a01, 0, 0, 0);
                a11 = __builtin_amdgcn_mfma_f32_16x16x32_bf16(ah1, blo1, a11, 0, 0, 0);
                a00 = __builtin_amdgcn_mfma_f32_16x16x32_bf16(al0, bh0,  a00, 0, 0, 0);
                a10 = __builtin_amdgcn_mfma_f32_16x16x32_bf16(al1, bh0,  a10, 0, 0, 0);
                a01 = __builtin_amdgcn_mfma_f32_16x16x32_bf16(al0, bh1,  a01, 0, 0, 0);
                a11 = __builtin_amdgcn_mfma_f32_16x16x32_bf16(al1, bh1,  a11, 0, 0, 0);
            }
            #pragma unroll
            for (int reg = 0; reg < 4; ++reg) {
                p[0][reg] += a00[reg] * a00[reg] + a01[reg] * a01[reg];
                p[1][reg] += a10[reg] * a10[reg] + a11[reg] * a11[reg];
            }
        }

        // epilogue: reduce across the 16 y-row lanes (l16), store 4 n's per quad
        #pragma unroll
        for (int mt = 0; mt < 2; ++mt) {
            float sv[4];
            #pragma unroll
            for (int reg = 0; reg < 4; ++reg) {
                float s = p[mt][reg];
                s += __shfl_xor(s, 1, 64);
                s += __shfl_xor(s, 2, 64);
                s += __shfl_xor(s, 4, 64);
                s += __shfl_xor(s, 8, 64);
                sv[reg] = s;
            }
            if (l16 == 0)
                *(float4*)&mrow[n0 + wave * 32 + mt * 16 + quad * 4] =
                    make_float4(sv[0], sv[1], sv[2], sv[3]);
        }
    }
}

// LSE + weights + totals from maha[16][NPAD].
__global__ __launch_bounds__(256) void finalize_kernel(const void* __restrict__ wsv,
                                                       float* __restrict__ out) {
    __shared__ float red[256];
    __shared__ float clds[16];

    const int tid = threadIdx.x;
    if (tid < 16) clds[tid] = ((const float*)((const char*)wsv + C_B))[tid];
    __syncthreads();

    const float* mahap = (const float*)((const char*)wsv + MAHA_B);
    const int n = blockIdx.x * 256 + tid;
    float esum = 0.0f;

    if (n < NN) {
        float ev[V];
        #pragma unroll
        for (int vv = 0; vv < V; ++vv) {
            float lp[KK];
            float m = -1e30f;
            #pragma unroll
            for (int k = 0; k < KK; ++k) {
                int r = vv * KK + k;
                lp[k] = -0.5f * mahap[(size_t)r * NPAD + n] + clds[r];
                m = fmaxf(m, lp[k]);
            }
            float s = 0.0f;
            #pragma unroll
            for (int k = 0; k < KK; ++k) s += expf(lp[k] - m);
            ev[vv] = -(m + logf(s));
        }
        float e0 = ev[0], e1 = ev[1];
        float m = fmaxf(-e0, -e1);
        float x0 = expf(-e0 - m);
        float x1 = expf(-e1 - m);
        float inv = 1.0f / (x0 + x1);
        out[(size_t)n * V + 0] = e0;
        out[(size_t)n * V + 1] = e1;
        out[OUT_W_OFF + (size_t)n * V + 0] = x0 * inv;
        out[OUT_W_OFF + (size_t)n * V + 1] = x1 * inv;
        esum = e0 + e1;
    }

    red[tid] = esum;
    __syncthreads();
    for (int s = 128; s > 0; s >>= 1) {
        if (tid < s) red[tid] += red[tid + s];
        __syncthreads();
    }
    if (tid == 0) atomicAdd(&out[OUT_TE], red[0]);
}

extern "C" void kernel_launch(void* const* d_in, const int* in_sizes, int n_in,
                              void* d_out, int out_size, void* d_ws, size_t ws_size,
                              hipStream_t stream) {
    const float* z     = (const float*)d_in[0];
    const float* phi   = (const float*)d_in[1];
    const float* mu    = (const float*)d_in[2];
    const float* sigma = (const float*)d_in[3];
    float* out = (float*)d_out;

    hipLaunchKernelGGL(zero_kernel, dim3(1), dim3(64), 0, stream, out);
    hipLaunchKernelGGL(prep_chol, dim3(V * KK), dim3(256), 0, stream, phi, mu, sigma, d_ws, out);
    hipLaunchKernelGGL(prep_trsm, dim3(64), dim3(256), 0, stream, d_ws);
    hipLaunchKernelGGL(maha_kernel, dim3(8 * CPX * 16), dim3(256), 0, stream, z, d_ws);
    hipLaunchKernelGGL(finalize_kernel, dim3((NPAD + 255) / 256), dim3(256), 0, stream, d_ws, out);
}

// Round 9
// 383.745 us; speedup vs baseline: 1.0272x; 1.0272x over previous
//
#include <hip/hip_runtime.h>
#include <math.h>

#define V 2
#define NN 100000
#define KK 8
#define DD 128
#define TILE_N 128
#define SL 132
#define NT 782            /* ceil(100000/128) */
#define CH 8              /* tiles per maha block */
#define CPX 13            /* chunks per XCD: 8*13=104 >= ceil(782/8)=98 */
#define NPAD 100096       /* NT*128 */
#define LOG2PI 1.8378770664093454f
#define LOG_1EM6 -13.815510557964274f

// Packed triangular W image (per r): 4 row-blocks of 32 rows; block b stores
// cols 0..32(b+1)-1, row stride 64(b+1) bytes. Within each block, the 16-byte
// chunk (ri, g) lives at byte ((ri*64*(b+1) + g*16) XOR ((ri&7)<<4)) — proven:
// bank conflicts 30.4M -> 4.8M. hi block byte bases {0,2048,6144,12288};
// lo copy at +20480 B. Total 40960 B.
#define IMG_PB 40960
#define IMG_LO_US 10240     /* ushort offset of lo half */

// ws layout (bytes):
//  IMG:  [16][40960]  packed+swizzled bf16 triangular image (hi then lo)
//  LF:   [16][69632]  L fp32 row-major stride 132 (67584 B used)
//  B:    [16][128] float
//  C:    [16] float
//  MAHA: [16][NPAD] float
#define LF_B   1114112
#define LF_STRIDE 69632
#define BV_B   2228224
#define C_B    2236416
#define MAHA_B 2236480

// out layout (floats): energies [N][V] | weights [N][V] | total_energies | total_penalty
#define OUT_W_OFF (NN*V)
#define OUT_TE (2*NN*V)
#define OUT_TP (2*NN*V + 1)

typedef __attribute__((ext_vector_type(8)))  short bf16x8;
typedef __attribute__((ext_vector_type(4)))  float f32x4;
typedef __attribute__((ext_vector_type(16))) float f32x16;
typedef __attribute__((ext_vector_type(4)))  unsigned u32x4;

__device__ __forceinline__ unsigned short f2bf_rtn(float f) {
    unsigned u = __builtin_bit_cast(unsigned, f);
    unsigned r = u + 0x7FFFu + ((u >> 16) & 1u);
    return (unsigned short)(r >> 16);
}
__device__ __forceinline__ float bf2f(unsigned short h) {
    unsigned u = ((unsigned)h) << 16;
    return __builtin_bit_cast(float, u);
}

// Cheap split: hi = truncation (packed 2-at-a-time via v_perm), lo = exact
// residual rounded half-up (proven rounds 0/2/3/5/6/7/8: absmax identical).
__device__ __forceinline__ void cvt_pair(float f0, float f1, unsigned& hi, unsigned& lo) {
    unsigned u0 = __builtin_bit_cast(unsigned, f0);
    unsigned u1 = __builtin_bit_cast(unsigned, f1);
    hi = __builtin_amdgcn_perm(u1, u0, 0x07060302u);   // [bf(f1) : bf(f0)]
    float r0 = f0 - __builtin_bit_cast(float, u0 & 0xFFFF0000u);
    float r1 = f1 - __builtin_bit_cast(float, u1 & 0xFFFF0000u);
    unsigned v0 = __builtin_bit_cast(unsigned, r0) + 0x8000u;
    unsigned v1 = __builtin_bit_cast(unsigned, r1) + 0x8000u;
    lo = __builtin_amdgcn_perm(v1, v0, 0x07060302u);
}

__global__ void zero_kernel(float* out) {
    int t = threadIdx.x;
    if (t < 2) out[OUT_TE + t] = 0.0f;
}

// One block of 256 threads per (v,k): panel Cholesky,
// forward solve L b = mu, write L + b + c + penalty/logdet.
__global__ __launch_bounds__(256) void prep_chol(const float* __restrict__ phi,
                                                 const float* __restrict__ mu,
                                                 const float* __restrict__ sigma,
                                                 void* __restrict__ wsv,
                                                 float* __restrict__ out) {
    __shared__ float Lf[DD * SL];          // L row-major, stride 132 (upper zeroed)
    __shared__ float P[8][SL];             // current panel, col-major
    __shared__ float dvec[DD];             // raw pivots d_c = L_cc^2
    __shared__ float mulds[DD];
    __shared__ float red[256];
    __shared__ float Bv[8];
    __shared__ float Bb[DD];

    const int tid = threadIdx.x;
    const int vk  = blockIdx.x;
    const int v   = vk >> 3;
    const int k   = vk & 7;
    const int R   = tid >> 4;
    const int C   = tid & 15;

    if (tid < DD) mulds[tid] = mu[vk * DD + tid];

    float A[8][8];
    const float* sig = sigma + (size_t)vk * DD * DD;
    float pen = 0.0f;
    #pragma unroll
    for (int a = 0; a < 8; ++a) {
        const float4* p4 = (const float4*)(sig + (size_t)(8 * R + a) * DD + 8 * C);
        float4 x = p4[0], y = p4[1];
        A[a][0] = x.x; A[a][1] = x.y; A[a][2] = x.z; A[a][3] = x.w;
        A[a][4] = y.x; A[a][5] = y.y; A[a][6] = y.z; A[a][7] = y.w;
        if (R == C) A[a][a] += 1e-6f;
    }
    if (R == C) {
        #pragma unroll
        for (int a = 0; a < 8; ++a) pen += 1.0f / (A[a][a] + 1e-12f);
    }

    for (int i = tid; i < DD * SL; i += 256) Lf[i] = 0.0f;

    red[tid] = pen;
    __syncthreads();
    for (int s = 128; s > 0; s >>= 1) {
        if (tid < s) red[tid] += red[tid + s];
        __syncthreads();
    }
    if (tid == 0) atomicAdd(&out[OUT_TP], red[0]);
    __syncthreads();

    // ---- 16 panel phases ----
    for (int p = 0; p < 16; ++p) {
        if (C == p && R >= p) {
            #pragma unroll
            for (int b = 0; b < 8; ++b) {
                *(float4*)&P[b][8 * R]     = make_float4(A[0][b], A[1][b], A[2][b], A[3][b]);
                *(float4*)&P[b][8 * R + 4] = make_float4(A[4][b], A[5][b], A[6][b], A[7][b]);
            }
        }
        __syncthreads();

        if (tid < 64) {
            const int lane = tid;
            const int r1 = 8 * p + lane;
            const int r2 = r1 + 64;
            const bool ok2 = (r2 < DD);
            float pr1[8], pr2[8], rs[8];
            #pragma unroll
            for (int j = 0; j < 8; ++j) {
                pr1[j] = (r1 < DD) ? P[j][r1] : 0.0f;
                pr2[j] = ok2 ? P[j][r2] : 0.0f;
            }
            #pragma unroll
            for (int j = 0; j < 8; ++j) {
                if (lane >= j && lane < 8) Bv[lane] = pr1[j];
                __builtin_amdgcn_wave_barrier();
                float bv[8];
                #pragma unroll
                for (int m = 0; m < 8; ++m) bv[m] = Bv[m];
                __builtin_amdgcn_wave_barrier();
                float piv = bv[j];
                if (lane == j) dvec[8 * p + j] = piv;
                float inv2 = 1.0f / piv;
                rs[j] = rsqrtf(piv);
                float m1 = pr1[j] * inv2;
                float m2 = pr2[j] * inv2;
                #pragma unroll
                for (int j2 = 0; j2 < 8; ++j2) {
                    if (j2 > j) {
                        if (lane > j) pr1[j2] -= m1 * bv[j2];
                        pr2[j2] -= m2 * bv[j2];
                    }
                }
            }
            #pragma unroll
            for (int j = 0; j < 8; ++j) {
                if (r1 < DD) {
                    float v1 = (lane >= j) ? pr1[j] * rs[j] : 0.0f;
                    P[j][r1] = v1;
                    Lf[r1 * SL + 8 * p + j] = v1;
                }
                if (ok2) {
                    float v2 = pr2[j] * rs[j];
                    P[j][r2] = v2;
                    Lf[r2 * SL + 8 * p + j] = v2;
                }
            }
        }
        __syncthreads();

        if (C > p && R >= p) {
            #pragma unroll
            for (int j = 0; j < 8; ++j) {
                float4 a0 = *(const float4*)&P[j][8 * R];
                float4 a1 = *(const float4*)&P[j][8 * R + 4];
                float4 b0 = *(const float4*)&P[j][8 * C];
                float4 b1 = *(const float4*)&P[j][8 * C + 4];
                float ra[8] = {a0.x, a0.y, a0.z, a0.w, a1.x, a1.y, a1.z, a1.w};
                float rb[8] = {b0.x, b0.y, b0.z, b0.w, b1.x, b1.y, b1.z, b1.w};
                #pragma unroll
                for (int a = 0; a < 8; ++a)
                    #pragma unroll
                    for (int b = 0; b < 8; ++b)
                        A[a][b] -= ra[a] * rb[b];
            }
        }
        __syncthreads();
    }

    // forward solve L b = mu (wave 0, wave-synchronous)
    if (tid < 64) {
        const int lane = tid;
        float acc0 = mulds[lane];
        float acc1 = mulds[lane + 64];
        for (int j = 0; j < DD; ++j) {
            if (j < 64) { if (lane == j)      Bb[j] = acc0 / Lf[j * SL + j]; }
            else        { if (lane == j - 64) Bb[j] = acc1 / Lf[j * SL + j]; }
            __builtin_amdgcn_wave_barrier();
            float bj = Bb[j];
            __builtin_amdgcn_wave_barrier();
            if (lane > j)      acc0 -= Lf[lane * SL + j] * bj;
            if (lane + 64 > j) acc1 -= Lf[(lane + 64) * SL + j] * bj;
        }
    }
    __syncthreads();
    if (tid < DD) ((float*)((char*)wsv + BV_B))[vk * DD + tid] = Bb[tid];

    // write L to global (fp32, stride 132)
    {
        float4* Lg = (float4*)((char*)wsv + LF_B + (size_t)vk * LF_STRIDE);
        const float4* Ls4 = (const float4*)Lf;
        for (int i = tid; i < DD * SL / 4; i += 256) Lg[i] = Ls4[i];
    }

    // logdet = sum log d_c (clipped) + c_k
    red[tid] = (tid < DD) ? logf(dvec[tid]) : 0.0f;
    __syncthreads();
    for (int s = 128; s > 0; s >>= 1) {
        if (tid < s) red[tid] += red[tid + s];
        __syncthreads();
    }
    if (tid == 0) {
        float logdet_c = fmaxf(red[0], LOG_1EM6);
        const float* ph = phi + v * KK;
        float m = ph[0];
        for (int i = 1; i < KK; ++i) m = fmaxf(m, ph[i]);
        float s = 0.0f;
        for (int i = 0; i < KK; ++i) s += expf(ph[i] - m);
        float logpi = ph[k] - m - logf(s);
        ((float*)((char*)wsv + C_B))[vk] = logpi - 0.5f * logdet_c - 0.5f * (float)DD * LOG2PI;
    }
}

// 64 blocks: (vk, column-group). Each block computes 32 columns of W = L^{-1}
// (8 lanes per column) and packs them into the packed+SWIZZLED triangular image.
__global__ __launch_bounds__(256) void prep_trsm(void* __restrict__ wsv) {
    __shared__ float Ls[DD * SL];
    __shared__ float Wc[32][SL];

    const int tid = threadIdx.x;
    const int vk  = blockIdx.x >> 2;
    const int cg  = blockIdx.x & 3;

    const float4* Lg = (const float4*)((const char*)wsv + LF_B + (size_t)vk * LF_STRIDE);
    float4* Ls4 = (float4*)Ls;
    for (int i = tid; i < DD * SL / 4; i += 256) Ls4[i] = Lg[i];
    __syncthreads();

    const int c   = tid >> 3;          // local column 0..31
    const int par = tid & 7;
    const int j   = 4 * c + cg;        // global column

    for (int e = par; e < SL; e += 8) Wc[c][e] = 0.0f;
    if (par == 0) Wc[c][j] = 1.0f / Ls[j * SL + j];
    __builtin_amdgcn_wave_barrier();

    const int pbase = j & ~3;
    for (int i = j + 1; i < DD; ++i) {
        float s = 0.0f;
        for (int p4 = pbase + 4 * par; p4 < i; p4 += 32) {
            float4 lf = *(const float4*)&Ls[i * SL + p4];
            float4 wc = *(const float4*)&Wc[c][p4];
            s += lf.x * wc.x + lf.y * wc.y + lf.z * wc.z + lf.w * wc.w;
        }
        s += __shfl_xor(s, 1, 64);
        s += __shfl_xor(s, 2, 64);
        s += __shfl_xor(s, 4, 64);
        if (par == 0) Wc[c][i] = -s / Ls[i * SL + i];
        __builtin_amdgcn_wave_barrier();
    }

    // pack column j into the packed+swizzled triangular image:
    // row i in row-block b=i>>5 (col stored only if (j>>5) <= b); chunk byte
    // offset within block = (ri*64*(b+1) + (j>>3)*16) ^ ((ri&7)<<4).
    unsigned short* Gh = (unsigned short*)((char*)wsv + (size_t)vk * IMG_PB);
    for (int i2 = par; i2 < DD; i2 += 8) {
        const int b = i2 >> 5;
        if ((j >> 5) > b) continue;            // col outside this block's range
        const int ri   = i2 & 31;
        const int hbb  = (b == 0 ? 0 : b == 1 ? 2048 : b == 2 ? 6144 : 12288);
        const int cb   = ri * 64 * (b + 1) + (j >> 3) * 16;
        const int sw   = cb ^ ((ri & 7) << 4);
        const int us   = ((hbb + sw) >> 1) + (j & 7);
        float f = (i2 >= j) ? Wc[c][i2] : 0.0f;
        unsigned short h = f2bf_rtn(f);
        unsigned short l = f2bf_rtn(f - bf2f(h));
        Gh[us] = h;
        Gh[us + IMG_LO_US] = l;
    }
}

// 1-D grid of 1664 blocks, XCD-aware decode (proven: FETCH 402->65MB).
// THIS ROUND: MFMA shape 16x16x32 -> 32x32x16 (same FLOPs, 60 instrs/wave-
// tile instead of 120, 8.07 vs 4.85 cyc => matrix cycles -17%). Operands:
// mfma(A=W from LDS, B=z from regs): A row=lane&31 (same image rows, same
// XOR swizzle, g=2s+(lane>>5)); B col=lane&31=n, 8 consecutive k per lane
// (same z addresses as before). D layout (m74/m101): lane holds 16 rows of
// ONE n => maha reduce is lane-local (16 squares) + one shfl_xor(32) —
// replaces the 4-step shfl tree. acc = 16+1 regs (was 24); epilogue b via
// 4 broadcast float4 LDS reads per row-block (same addr across lanes: free).
__global__ __launch_bounds__(256) void maha_kernel(const float* __restrict__ z,
                                                   void* __restrict__ wsv) {
    __shared__ unsigned short wl[IMG_PB / 2];
    __shared__ float bl_s[DD];

    const int tid  = threadIdx.x;
    const int lane = tid & 63;
    const int wave = tid >> 6;
    const int rl   = lane & 31;         // W-row-local == n-local
    const int h    = lane >> 5;         // k-half selector
    const int swz  = (lane & 7) << 4;   // read-side XOR (rows map to lane&31)

    const int bi    = blockIdx.x;       // 0..1663
    const int xcd   = bi & 7;
    const int jj    = bi >> 3;          // 0..207
    const int r     = jj & 15;          // fast: 16 r's of a chunk adjacent on XCD
    const int lc    = jj >> 4;          // 0..12
    const int chunk = xcd * CPX + lc;   // 0..103
    const int vv    = r >> 3;

    if (chunk * CH >= NT) return;       // fully-empty chunk (98..103): skip staging

    // stage packed W_r (10 x 4KB chunks, exact: IMG_PB = 10*4096) — linear
    // copy; the swizzle already lives in the global image.
    {
        const char* src = (const char*)wsv + (size_t)r * IMG_PB;
        char* dst = (char*)wl;
        const int lane_off = wave * 1024 + lane * 16;
        #pragma unroll
        for (int t = 0; t < 10; ++t)
            __builtin_amdgcn_global_load_lds(
                (const __attribute__((address_space(1))) void*)(src + t * 4096 + lane_off),
                (__attribute__((address_space(3))) void*)(dst + t * 4096 + wave * 1024),
                16, 0, 0);
    }
    if (tid < DD) bl_s[tid] = ((const float*)((const char*)wsv + BV_B))[r * DD + tid];
    __syncthreads();   // single drain; nothing in-flight afterwards

    const float* zbase = z + (size_t)vv * NN * DD;
    float* mrow = (float*)((char*)wsv + MAHA_B) + (size_t)r * NPAD;
    const char* wlb = (const char*)wl;

    for (int ti = 0; ti < CH; ++ti) {
        const int t = chunk * CH + ti;
        if (t >= NT) break;
        const int n0 = t * TILE_N;

        // load this lane's z fragments: n = n0+wave*32+rl, k = s*16 + h*8 + 0..7
        const int n   = n0 + wave * 32 + rl;
        const bool ok = (n < NN);
        const float* zp = zbase + (size_t)n * DD + h * 8;

        float4 raw[8][2];
        #pragma unroll
        for (int s = 0; s < 8; ++s) {
            if (ok) {
                raw[s][0] = *(const float4*)(zp + s * 16);
                raw[s][1] = *(const float4*)(zp + s * 16 + 4);
            } else {
                raw[s][0] = make_float4(0.f, 0.f, 0.f, 0.f);
                raw[s][1] = make_float4(0.f, 0.f, 0.f, 0.f);
            }
        }

        u32x4 zh8[8], zl8[8];
        #pragma unroll
        for (int s = 0; s < 8; ++s) {
            float4 a = raw[s][0];
            float4 b = raw[s][1];
            unsigned h0, l0, h1, l1, h2, l2, h3, l3;
            cvt_pair(a.x, a.y, h0, l0);
            cvt_pair(a.z, a.w, h1, l1);
            cvt_pair(b.x, b.y, h2, l2);
            cvt_pair(b.z, b.w, h3, l3);
            u32x4 th, tl;
            th[0] = h0; th[1] = h1; th[2] = h2; th[3] = h3;
            tl[0] = l0; tl[1] = l1; tl[2] = l2; tl[3] = l3;
            zh8[s] = th;
            zl8[s] = tl;
        }

        // row-block loop: per R one 32x32 D tile (16 regs), triangular K
        // (s <= 2R+1), 3 split products per (R,s) sharing 2 LDS reads.
        float pa = 0.0f;
        #pragma unroll
        for (int R = 0; R < 4; ++R) {
            const int hb = (R == 0 ? 0 : R == 1 ? 2048 : R == 2 ? 6144 : 12288);
            const int st = 64 * (R + 1);
            f32x16 D = (f32x16)(0.0f);
            #pragma unroll
            for (int s = 0; s <= 2 * R + 1; ++s) {
                const int g   = 2 * s + h;
                const int off = hb + ((rl * st + g * 16) ^ swz);
                bf16x8 wh  = *(const bf16x8*)(wlb + off);
                bf16x8 wlo = *(const bf16x8*)(wlb + off + 2 * IMG_LO_US);
                bf16x8 zh = __builtin_bit_cast(bf16x8, zh8[s]);
                bf16x8 zl = __builtin_bit_cast(bf16x8, zl8[s]);
                D = __builtin_amdgcn_mfma_f32_32x32x16_bf16(wh,  zh, D, 0, 0, 0);
                D = __builtin_amdgcn_mfma_f32_32x32x16_bf16(wlo, zh, D, 0, 0, 0);
                D = __builtin_amdgcn_mfma_f32_32x32x16_bf16(wh,  zl, D, 0, 0, 0);
            }
            // rows for regs 4q..4q+3: 32R + 8q + 4h + {0,1,2,3} (consecutive)
            #pragma unroll
            for (int q = 0; q < 4; ++q) {
                float4 bq = *(const float4*)&bl_s[32 * R + 8 * q + 4 * h];
                float t0 = D[4 * q + 0] - bq.x;
                float t1 = D[4 * q + 1] - bq.y;
                float t2 = D[4 * q + 2] - bq.z;
                float t3 = D[4 * q + 3] - bq.w;
                pa += t0 * t0 + t1 * t1 + t2 * t2 + t3 * t3;
            }
        }

        // lane l holds half the rows for n; partner l^32 holds the other half
        pa += __shfl_xor(pa, 32, 64);
        if (lane < 32) mrow[n0 + wave * 32 + rl] = pa;
    }
}

// LSE + weights + totals from maha[16][NPAD].
__global__ __launch_bounds__(256) void finalize_kernel(const void* __restrict__ wsv,
                                                       float* __restrict__ out) {
    __shared__ float red[256];
    __shared__ float clds[16];

    const int tid = threadIdx.x;
    if (tid < 16) clds[tid] = ((const float*)((const char*)wsv + C_B))[tid];
    __syncthreads();

    const float* mahap = (const float*)((const char*)wsv + MAHA_B);
    const int n = blockIdx.x * 256 + tid;
    float esum = 0.0f;

    if (n < NN) {
        float ev[V];
        #pragma unroll
        for (int vv = 0; vv < V; ++vv) {
            float lp[KK];
            float m = -1e30f;
            #pragma unroll
            for (int k = 0; k < KK; ++k) {
                int r = vv * KK + k;
                lp[k] = -0.5f * mahap[(size_t)r * NPAD + n] + clds[r];
                m = fmaxf(m, lp[k]);
            }
            float s = 0.0f;
            #pragma unroll
            for (int k = 0; k < KK; ++k) s += expf(lp[k] - m);
            ev[vv] = -(m + logf(s));
        }
        float e0 = ev[0], e1 = ev[1];
        float m = fmaxf(-e0, -e1);
        float x0 = expf(-e0 - m);
        float x1 = expf(-e1 - m);
        float inv = 1.0f / (x0 + x1);
        out[(size_t)n * V + 0] = e0;
        out[(size_t)n * V + 1] = e1;
        out[OUT_W_OFF + (size_t)n * V + 0] = x0 * inv;
        out[OUT_W_OFF + (size_t)n * V + 1] = x1 * inv;
        esum = e0 + e1;
    }

    red[tid] = esum;
    __syncthreads();
    for (int s = 128; s > 0; s >>= 1) {
        if (tid < s) red[tid] += red[tid + s];
        __syncthreads();
    }
    if (tid == 0) atomicAdd(&out[OUT_TE], red[0]);
}

extern "C" void kernel_launch(void* const* d_in, const int* in_sizes, int n_in,
                              void* d_out, int out_size, void* d_ws, size_t ws_size,
                              hipStream_t stream) {
    const float* z     = (const float*)d_in[0];
    const float* phi   = (const float*)d_in[1];
    const float* mu    = (const float*)d_in[2];
    const float* sigma = (const float*)d_in[3];
    float* out = (float*)d_out;

    hipLaunchKernelGGL(zero_kernel, dim3(1), dim3(64), 0, stream, out);
    hipLaunchKernelGGL(prep_chol, dim3(V * KK), dim3(256), 0, stream, phi, mu, sigma, d_ws, out);
    hipLaunchKernelGGL(prep_trsm, dim3(64), dim3(256), 0, stream, d_ws);
    hipLaunchKernelGGL(maha_kernel, dim3(8 * CPX * 16), dim3(256), 0, stream, z, d_ws);
    hipLaunchKernelGGL(finalize_kernel, dim3((NPAD + 255) / 256), dim3(256), 0, stream, d_ws, out);
}

// Round 10
// 369.933 us; speedup vs baseline: 1.0656x; 1.0373x over previous
//
#include <hip/hip_runtime.h>
#include <math.h>

#define V 2
#define NN 100000
#define KK 8
#define DD 128
#define TILE_N 128
#define SL 132
#define NT 782            /* ceil(100000/128) */
#define CH 7              /* tiles per maha block */
#define CPX 14            /* chunks per XCD: 8*14 = 112 = ceil(782/7) exactly */
#define NPAD 100096       /* NT*128 */
#define LOG2PI 1.8378770664093454f
#define LOG_1EM6 -13.815510557964274f

// Packed triangular W image (per r), COLUMN-MAJOR-BY-CHUNK layout:
// 4 row-blocks of 32 rows; block R stores g-slots 0..4R+3 (cols 0..32(R+1)-1).
// 16B chunk (R, g, rl) lives at byte hbase[R] + g*512 + rl*16, hbase =
// {0,2048,6144,12288}; lo copy at +20480 B. A half-wave (32 lanes, fixed g)
// reads a CONTIGUOUS 512B block -> minimal 4-phase LDS access, ZERO bank
// conflicts (round 9's XOR swizzle couldn't de-alias 32 rows at 64B row
// stride: 8M conflict cycles). Also: per-read LDS address becomes one vaddr
// (h*512+rl*16) + compile-time offset immediate. Total 40960 B.
#define IMG_PB 40960
#define IMG_LO_US 10240     /* ushort offset of lo half */

// ws layout (bytes):
//  IMG:  [16][40960]  packed bf16 triangular image (hi then lo)
//  LF:   [16][69632]  L fp32 row-major stride 132 (67584 B used)
//  B:    [16][128] float
//  C:    [16] float
//  MAHA: [16][NPAD] float
#define LF_B   1114112
#define LF_STRIDE 69632
#define BV_B   2228224
#define C_B    2236416
#define MAHA_B 2236480

// out layout (floats): energies [N][V] | weights [N][V] | total_energies | total_penalty
#define OUT_W_OFF (NN*V)
#define OUT_TE (2*NN*V)
#define OUT_TP (2*NN*V + 1)

typedef __attribute__((ext_vector_type(8)))  short bf16x8;
typedef __attribute__((ext_vector_type(4)))  float f32x4;
typedef __attribute__((ext_vector_type(16))) float f32x16;
typedef __attribute__((ext_vector_type(4)))  unsigned u32x4;

__device__ __forceinline__ unsigned short f2bf_rtn(float f) {
    unsigned u = __builtin_bit_cast(unsigned, f);
    unsigned r = u + 0x7FFFu + ((u >> 16) & 1u);
    return (unsigned short)(r >> 16);
}
__device__ __forceinline__ float bf2f(unsigned short h) {
    unsigned u = ((unsigned)h) << 16;
    return __builtin_bit_cast(float, u);
}

// Cheap split: hi = truncation (packed 2-at-a-time via v_perm), lo = exact
// residual rounded half-up (proven rounds 0/2/3/5-9: absmax identical).
__device__ __forceinline__ void cvt_pair(float f0, float f1, unsigned& hi, unsigned& lo) {
    unsigned u0 = __builtin_bit_cast(unsigned, f0);
    unsigned u1 = __builtin_bit_cast(unsigned, f1);
    hi = __builtin_amdgcn_perm(u1, u0, 0x07060302u);   // [bf(f1) : bf(f0)]
    float r0 = f0 - __builtin_bit_cast(float, u0 & 0xFFFF0000u);
    float r1 = f1 - __builtin_bit_cast(float, u1 & 0xFFFF0000u);
    unsigned v0 = __builtin_bit_cast(unsigned, r0) + 0x8000u;
    unsigned v1 = __builtin_bit_cast(unsigned, r1) + 0x8000u;
    lo = __builtin_amdgcn_perm(v1, v0, 0x07060302u);
}

__global__ void zero_kernel(float* out) {
    int t = threadIdx.x;
    if (t < 2) out[OUT_TE + t] = 0.0f;
}

// One block of 256 threads per (v,k): panel Cholesky,
// forward solve L b = mu, write L + b + c + penalty/logdet.
__global__ __launch_bounds__(256) void prep_chol(const float* __restrict__ phi,
                                                 const float* __restrict__ mu,
                                                 const float* __restrict__ sigma,
                                                 void* __restrict__ wsv,
                                                 float* __restrict__ out) {
    __shared__ float Lf[DD * SL];          // L row-major, stride 132 (upper zeroed)
    __shared__ float P[8][SL];             // current panel, col-major
    __shared__ float dvec[DD];             // raw pivots d_c = L_cc^2
    __shared__ float mulds[DD];
    __shared__ float red[256];
    __shared__ float Bv[8];
    __shared__ float Bb[DD];

    const int tid = threadIdx.x;
    const int vk  = blockIdx.x;
    const int v   = vk >> 3;
    const int k   = vk & 7;
    const int R   = tid >> 4;
    const int C   = tid & 15;

    if (tid < DD) mulds[tid] = mu[vk * DD + tid];

    float A[8][8];
    const float* sig = sigma + (size_t)vk * DD * DD;
    float pen = 0.0f;
    #pragma unroll
    for (int a = 0; a < 8; ++a) {
        const float4* p4 = (const float4*)(sig + (size_t)(8 * R + a) * DD + 8 * C);
        float4 x = p4[0], y = p4[1];
        A[a][0] = x.x; A[a][1] = x.y; A[a][2] = x.z; A[a][3] = x.w;
        A[a][4] = y.x; A[a][5] = y.y; A[a][6] = y.z; A[a][7] = y.w;
        if (R == C) A[a][a] += 1e-6f;
    }
    if (R == C) {
        #pragma unroll
        for (int a = 0; a < 8; ++a) pen += 1.0f / (A[a][a] + 1e-12f);
    }

    for (int i = tid; i < DD * SL; i += 256) Lf[i] = 0.0f;

    red[tid] = pen;
    __syncthreads();
    for (int s = 128; s > 0; s >>= 1) {
        if (tid < s) red[tid] += red[tid + s];
        __syncthreads();
    }
    if (tid == 0) atomicAdd(&out[OUT_TP], red[0]);
    __syncthreads();

    // ---- 16 panel phases ----
    for (int p = 0; p < 16; ++p) {
        if (C == p && R >= p) {
            #pragma unroll
            for (int b = 0; b < 8; ++b) {
                *(float4*)&P[b][8 * R]     = make_float4(A[0][b], A[1][b], A[2][b], A[3][b]);
                *(float4*)&P[b][8 * R + 4] = make_float4(A[4][b], A[5][b], A[6][b], A[7][b]);
            }
        }
        __syncthreads();

        if (tid < 64) {
            const int lane = tid;
            const int r1 = 8 * p + lane;
            const int r2 = r1 + 64;
            const bool ok2 = (r2 < DD);
            float pr1[8], pr2[8], rs[8];
            #pragma unroll
            for (int j = 0; j < 8; ++j) {
                pr1[j] = (r1 < DD) ? P[j][r1] : 0.0f;
                pr2[j] = ok2 ? P[j][r2] : 0.0f;
            }
            #pragma unroll
            for (int j = 0; j < 8; ++j) {
                if (lane >= j && lane < 8) Bv[lane] = pr1[j];
                __builtin_amdgcn_wave_barrier();
                float bv[8];
                #pragma unroll
                for (int m = 0; m < 8; ++m) bv[m] = Bv[m];
                __builtin_amdgcn_wave_barrier();
                float piv = bv[j];
                if (lane == j) dvec[8 * p + j] = piv;
                float inv2 = 1.0f / piv;
                rs[j] = rsqrtf(piv);
                float m1 = pr1[j] * inv2;
                float m2 = pr2[j] * inv2;
                #pragma unroll
                for (int j2 = 0; j2 < 8; ++j2) {
                    if (j2 > j) {
                        if (lane > j) pr1[j2] -= m1 * bv[j2];
                        pr2[j2] -= m2 * bv[j2];
                    }
                }
            }
            #pragma unroll
            for (int j = 0; j < 8; ++j) {
                if (r1 < DD) {
                    float v1 = (lane >= j) ? pr1[j] * rs[j] : 0.0f;
                    P[j][r1] = v1;
                    Lf[r1 * SL + 8 * p + j] = v1;
                }
                if (ok2) {
                    float v2 = pr2[j] * rs[j];
                    P[j][r2] = v2;
                    Lf[r2 * SL + 8 * p + j] = v2;
                }
            }
        }
        __syncthreads();

        if (C > p && R >= p) {
            #pragma unroll
            for (int j = 0; j < 8; ++j) {
                float4 a0 = *(const float4*)&P[j][8 * R];
                float4 a1 = *(const float4*)&P[j][8 * R + 4];
                float4 b0 = *(const float4*)&P[j][8 * C];
                float4 b1 = *(const float4*)&P[j][8 * C + 4];
                float ra[8] = {a0.x, a0.y, a0.z, a0.w, a1.x, a1.y, a1.z, a1.w};
                float rb[8] = {b0.x, b0.y, b0.z, b0.w, b1.x, b1.y, b1.z, b1.w};
                #pragma unroll
                for (int a = 0; a < 8; ++a)
                    #pragma unroll
                    for (int b = 0; b < 8; ++b)
                        A[a][b] -= ra[a] * rb[b];
            }
        }
        __syncthreads();
    }

    // forward solve L b = mu (wave 0, wave-synchronous)
    if (tid < 64) {
        const int lane = tid;
        float acc0 = mulds[lane];
        float acc1 = mulds[lane + 64];
        for (int j = 0; j < DD; ++j) {
            if (j < 64) { if (lane == j)      Bb[j] = acc0 / Lf[j * SL + j]; }
            else        { if (lane == j - 64) Bb[j] = acc1 / Lf[j * SL + j]; }
            __builtin_amdgcn_wave_barrier();
            float bj = Bb[j];
            __builtin_amdgcn_wave_barrier();
            if (lane > j)      acc0 -= Lf[lane * SL + j] * bj;
            if (lane + 64 > j) acc1 -= Lf[(lane + 64) * SL + j] * bj;
        }
    }
    __syncthreads();
    if (tid < DD) ((float*)((char*)wsv + BV_B))[vk * DD + tid] = Bb[tid];

    // write L to global (fp32, stride 132)
    {
        float4* Lg = (float4*)((char*)wsv + LF_B + (size_t)vk * LF_STRIDE);
        const float4* Ls4 = (const float4*)Lf;
        for (int i = tid; i < DD * SL / 4; i += 256) Lg[i] = Ls4[i];
    }

    // logdet = sum log d_c (clipped) + c_k
    red[tid] = (tid < DD) ? logf(dvec[tid]) : 0.0f;
    __syncthreads();
    for (int s = 128; s > 0; s >>= 1) {
        if (tid < s) red[tid] += red[tid + s];
        __syncthreads();
    }
    if (tid == 0) {
        float logdet_c = fmaxf(red[0], LOG_1EM6);
        const float* ph = phi + v * KK;
        float m = ph[0];
        for (int i = 1; i < KK; ++i) m = fmaxf(m, ph[i]);
        float s = 0.0f;
        for (int i = 0; i < KK; ++i) s += expf(ph[i] - m);
        float logpi = ph[k] - m - logf(s);
        ((float*)((char*)wsv + C_B))[vk] = logpi - 0.5f * logdet_c - 0.5f * (float)DD * LOG2PI;
    }
}

// 64 blocks: (vk, column-group). Each block computes 32 columns of W = L^{-1}
// (8 lanes per column) and packs them into the column-major-chunk image.
__global__ __launch_bounds__(256) void prep_trsm(void* __restrict__ wsv) {
    __shared__ float Ls[DD * SL];
    __shared__ float Wc[32][SL];

    const int tid = threadIdx.x;
    const int vk  = blockIdx.x >> 2;
    const int cg  = blockIdx.x & 3;

    const float4* Lg = (const float4*)((const char*)wsv + LF_B + (size_t)vk * LF_STRIDE);
    float4* Ls4 = (float4*)Ls;
    for (int i = tid; i < DD * SL / 4; i += 256) Ls4[i] = Lg[i];
    __syncthreads();

    const int c   = tid >> 3;          // local column 0..31
    const int par = tid & 7;
    const int j   = 4 * c + cg;        // global column

    for (int e = par; e < SL; e += 8) Wc[c][e] = 0.0f;
    if (par == 0) Wc[c][j] = 1.0f / Ls[j * SL + j];
    __builtin_amdgcn_wave_barrier();

    const int pbase = j & ~3;
    for (int i = j + 1; i < DD; ++i) {
        float s = 0.0f;
        for (int p4 = pbase + 4 * par; p4 < i; p4 += 32) {
            float4 lf = *(const float4*)&Ls[i * SL + p4];
            float4 wc = *(const float4*)&Wc[c][p4];
            s += lf.x * wc.x + lf.y * wc.y + lf.z * wc.z + lf.w * wc.w;
        }
        s += __shfl_xor(s, 1, 64);
        s += __shfl_xor(s, 2, 64);
        s += __shfl_xor(s, 4, 64);
        if (par == 0) Wc[c][i] = -s / Ls[i * SL + i];
        __builtin_amdgcn_wave_barrier();
    }

    // pack column j into the column-major-chunk image:
    // element (i,j): R=i>>5 (stored iff j>>5 <= R), g=j>>3, rl=i&31;
    // ushort idx = hbus[R] + g*256 + rl*8 + (j&7); lo at +IMG_LO_US.
    unsigned short* Gh = (unsigned short*)((char*)wsv + (size_t)vk * IMG_PB);
    for (int i2 = par; i2 < DD; i2 += 8) {
        const int b = i2 >> 5;
        if ((j >> 5) > b) continue;            // col outside this block's range
        const int rl   = i2 & 31;
        const int hbus = (b == 0 ? 0 : b == 1 ? 1024 : b == 2 ? 3072 : 6144);
        const int us   = hbus + (j >> 3) * 256 + rl * 8 + (j & 7);
        float f = (i2 >= j) ? Wc[c][i2] : 0.0f;
        unsigned short hsh = f2bf_rtn(f);
        unsigned short lsh = f2bf_rtn(f - bf2f(hsh));
        Gh[us] = hsh;
        Gh[us + IMG_LO_US] = lsh;
    }
}

// 1-D grid of 1792 blocks, XCD-aware decode: CH=7 -> 112 chunks = exactly
// 14 per XCD (perfect balance, critical path 98 tiles vs round-9's 104; no
// empty blocks). 32x32x16 MFMA (proven round 9: -8%). Column-major-chunk
// LDS layout: half-wave reads are contiguous 512B -> zero bank conflicts,
// and all 40 ds_reads share ONE vaddr (h*512+rl*16) + offset immediates.
__global__ __launch_bounds__(256) void maha_kernel(const float* __restrict__ z,
                                                   void* __restrict__ wsv) {
    __shared__ unsigned short wl[IMG_PB / 2];
    __shared__ float bl_s[DD];

    const int tid  = threadIdx.x;
    const int lane = tid & 63;
    const int wave = tid >> 6;
    const int rl   = lane & 31;         // W-row-local == n-local
    const int h    = lane >> 5;         // k-half selector

    const int bi    = blockIdx.x;       // 0..1791
    const int xcd   = bi & 7;
    const int jj    = bi >> 3;          // 0..223
    const int r     = jj & 15;          // fast: 16 r's of a chunk adjacent on XCD
    const int lc    = jj >> 4;          // 0..13
    const int chunk = xcd * CPX + lc;   // 0..111
    const int vv    = r >> 3;

    // stage packed W_r (10 x 4KB chunks, exact: IMG_PB = 10*4096) — linear copy
    {
        const char* src = (const char*)wsv + (size_t)r * IMG_PB;
        char* dst = (char*)wl;
        const int lane_off = wave * 1024 + lane * 16;
        #pragma unroll
        for (int t = 0; t < 10; ++t)
            __builtin_amdgcn_global_load_lds(
                (const __attribute__((address_space(1))) void*)(src + t * 4096 + lane_off),
                (__attribute__((address_space(3))) void*)(dst + t * 4096 + wave * 1024),
                16, 0, 0);
    }
    if (tid < DD) bl_s[tid] = ((const float*)((const char*)wsv + BV_B))[r * DD + tid];
    __syncthreads();   // single drain; nothing in-flight afterwards

    const float* zbase = z + (size_t)vv * NN * DD;
    float* mrow = (float*)((char*)wsv + MAHA_B) + (size_t)r * NPAD;
    const char* wlb = (const char*)wl + (h * 512 + rl * 16);   // single vaddr base

    for (int ti = 0; ti < CH; ++ti) {
        const int t = chunk * CH + ti;
        if (t >= NT) break;
        const int n0 = t * TILE_N;

        // load this lane's z fragments: n = n0+wave*32+rl, k = s*16 + h*8 + 0..7
        const int n   = n0 + wave * 32 + rl;
        const bool ok = (n < NN);
        const float* zp = zbase + (size_t)n * DD + h * 8;

        float4 raw[8][2];
        #pragma unroll
        for (int s = 0; s < 8; ++s) {
            if (ok) {
                raw[s][0] = *(const float4*)(zp + s * 16);
                raw[s][1] = *(const float4*)(zp + s * 16 + 4);
            } else {
                raw[s][0] = make_float4(0.f, 0.f, 0.f, 0.f);
                raw[s][1] = make_float4(0.f, 0.f, 0.f, 0.f);
            }
        }

        u32x4 zh8[8], zl8[8];
        #pragma unroll
        for (int s = 0; s < 8; ++s) {
            float4 a = raw[s][0];
            float4 b = raw[s][1];
            unsigned h0, l0, h1, l1, h2, l2, h3, l3;
            cvt_pair(a.x, a.y, h0, l0);
            cvt_pair(a.z, a.w, h1, l1);
            cvt_pair(b.x, b.y, h2, l2);
            cvt_pair(b.z, b.w, h3, l3);
            u32x4 th, tl;
            th[0] = h0; th[1] = h1; th[2] = h2; th[3] = h3;
            tl[0] = l0; tl[1] = l1; tl[2] = l2; tl[3] = l3;
            zh8[s] = th;
            zl8[s] = tl;
        }

        // row-block loop: per R one 32x32 D tile (16 regs), triangular K
        // (s <= 2R+1), 3 split products per (R,s) sharing 2 LDS reads.
        // LDS read: base vaddr + compile-time offset hb + 1024*s (hi),
        // +20480 (lo) — contiguous 512B per half-wave, conflict-free.
        float pa = 0.0f;
        #pragma unroll
        for (int R = 0; R < 4; ++R) {
            const int hb = (R == 0 ? 0 : R == 1 ? 2048 : R == 2 ? 6144 : 12288);
            f32x16 D = (f32x16)(0.0f);
            #pragma unroll
            for (int s = 0; s <= 2 * R + 1; ++s) {
                const int off = hb + 1024 * s;       // + vaddr's h*512 gives g=2s+h
                bf16x8 wh  = *(const bf16x8*)(wlb + off);
                bf16x8 wlo = *(const bf16x8*)(wlb + off + 2 * IMG_LO_US);
                bf16x8 zh = __builtin_bit_cast(bf16x8, zh8[s]);
                bf16x8 zl = __builtin_bit_cast(bf16x8, zl8[s]);
                D = __builtin_amdgcn_mfma_f32_32x32x16_bf16(wh,  zh, D, 0, 0, 0);
                D = __builtin_amdgcn_mfma_f32_32x32x16_bf16(wlo, zh, D, 0, 0, 0);
                D = __builtin_amdgcn_mfma_f32_32x32x16_bf16(wh,  zl, D, 0, 0, 0);
            }
            // rows for regs 4q..4q+3: 32R + 8q + 4h + {0,1,2,3} (consecutive)
            #pragma unroll
            for (int q = 0; q < 4; ++q) {
                float4 bq = *(const float4*)&bl_s[32 * R + 8 * q + 4 * h];
                float t0 = D[4 * q + 0] - bq.x;
                float t1 = D[4 * q + 1] - bq.y;
                float t2 = D[4 * q + 2] - bq.z;
                float t3 = D[4 * q + 3] - bq.w;
                pa += t0 * t0 + t1 * t1 + t2 * t2 + t3 * t3;
            }
        }

        // lane l holds half the rows for n; partner l^32 holds the other half
        pa += __shfl_xor(pa, 32, 64);
        if (lane < 32) mrow[n0 + wave * 32 + rl] = pa;
    }
}

// LSE + weights + totals from maha[16][NPAD].
__global__ __launch_bounds__(256) void finalize_kernel(const void* __restrict__ wsv,
                                                       float* __restrict__ out) {
    __shared__ float red[256];
    __shared__ float clds[16];

    const int tid = threadIdx.x;
    if (tid < 16) clds[tid] = ((const float*)((const char*)wsv + C_B))[tid];
    __syncthreads();

    const float* mahap = (const float*)((const char*)wsv + MAHA_B);
    const int n = blockIdx.x * 256 + tid;
    float esum = 0.0f;

    if (n < NN) {
        float ev[V];
        #pragma unroll
        for (int vv = 0; vv < V; ++vv) {
            float lp[KK];
            float m = -1e30f;
            #pragma unroll
            for (int k = 0; k < KK; ++k) {
                int r = vv * KK + k;
                lp[k] = -0.5f * mahap[(size_t)r * NPAD + n] + clds[r];
                m = fmaxf(m, lp[k]);
            }
            float s = 0.0f;
            #pragma unroll
            for (int k = 0; k < KK; ++k) s += expf(lp[k] - m);
            ev[vv] = -(m + logf(s));
        }
        float e0 = ev[0], e1 = ev[1];
        float m = fmaxf(-e0, -e1);
        float x0 = expf(-e0 - m);
        float x1 = expf(-e1 - m);
        float inv = 1.0f / (x0 + x1);
        out[(size_t)n * V + 0] = e0;
        out[(size_t)n * V + 1] = e1;
        out[OUT_W_OFF + (size_t)n * V + 0] = x0 * inv;
        out[OUT_W_OFF + (size_t)n * V + 1] = x1 * inv;
        esum = e0 + e1;
    }

    red[tid] = esum;
    __syncthreads();
    for (int s = 128; s > 0; s >>= 1) {
        if (tid < s) red[tid] += red[tid + s];
        __syncthreads();
    }
    if (tid == 0) atomicAdd(&out[OUT_TE], red[0]);
}

extern "C" void kernel_launch(void* const* d_in, const int* in_sizes, int n_in,
                              void* d_out, int out_size, void* d_ws, size_t ws_size,
                              hipStream_t stream) {
    const float* z     = (const float*)d_in[0];
    const float* phi   = (const float*)d_in[1];
    const float* mu    = (const float*)d_in[2];
    const float* sigma = (const float*)d_in[3];
    float* out = (float*)d_out;

    hipLaunchKernelGGL(zero_kernel, dim3(1), dim3(64), 0, stream, out);
    hipLaunchKernelGGL(prep_chol, dim3(V * KK), dim3(256), 0, stream, phi, mu, sigma, d_ws, out);
    hipLaunchKernelGGL(prep_trsm, dim3(64), dim3(256), 0, stream, d_ws);
    hipLaunchKernelGGL(maha_kernel, dim3(8 * CPX * 16), dim3(256), 0, stream, z, d_ws);
    hipLaunchKernelGGL(finalize_kernel, dim3((NPAD + 255) / 256), dim3(256), 0, stream, d_ws, out);
}